// Round 18
// baseline (188.441 us; speedup 1.0000x reference)
//
#include <hip/hip_runtime.h>
#include <hip/hip_fp16.h>

#define N_NODES 50000
#define N_EDGES 800000
#define IN_F 128
#define HID 96
#define NCLS 21
#define NBUCK 196        // coarse bucket = tgt>>8  (49999>>8 = 195)
#define BCAP  4608       // per-bucket capacity: mean 4082, +8 sigma
#define CPAD  16         // cursor stride in ints -> one 64B line per counter

typedef _Float16 f16x8 __attribute__((ext_vector_type(8)));
typedef float f32x4 __attribute__((ext_vector_type(4)));

// ---------------- zero ----------------
__global__ void k_zero_int(int* __restrict__ p, int n) {
  int i = blockIdx.x * blockDim.x + threadIdx.x;
  if (i < n) p[i] = 0;
}

// ---------------- pass 1: bin edges by tgt>>8 ----------------
__global__ __launch_bounds__(1024) void k_bin(
    const int* __restrict__ src, const int* __restrict__ tgt,
    int* __restrict__ cursor, int* __restrict__ packed) {
  __shared__ int lhist[NBUCK];
  __shared__ int gbase[NBUCK];
  int tid = threadIdx.x;
  if (tid < NBUCK) lhist[tid] = 0;
  __syncthreads();
  int me = blockIdx.x * 4096 + tid * 4;
  int4 t4, s4;
  int b0 = 0, b1 = 0, b2 = 0, b3 = 0;
  bool valid = me < N_EDGES;
  if (valid) {
    t4 = *reinterpret_cast<const int4*>(tgt + me);
    s4 = *reinterpret_cast<const int4*>(src + me);
    b0 = t4.x >> 8; b1 = t4.y >> 8; b2 = t4.z >> 8; b3 = t4.w >> 8;
    atomicAdd(&lhist[b0], 1); atomicAdd(&lhist[b1], 1);
    atomicAdd(&lhist[b2], 1); atomicAdd(&lhist[b3], 1);
  }
  __syncthreads();
  if (tid < NBUCK) {
    int c = lhist[tid];
    gbase[tid] = c ? atomicAdd(&cursor[tid * CPAD], c) : 0;
    lhist[tid] = 0;
  }
  __syncthreads();
  if (valid) {
    int r, pos;
    r = atomicAdd(&lhist[b0], 1);
    pos = gbase[b0] + r;
    if (pos < BCAP) packed[b0 * BCAP + pos] = (s4.x << 8) | (t4.x & 255);
    r = atomicAdd(&lhist[b1], 1);
    pos = gbase[b1] + r;
    if (pos < BCAP) packed[b1 * BCAP + pos] = (s4.y << 8) | (t4.y & 255);
    r = atomicAdd(&lhist[b2], 1);
    pos = gbase[b2] + r;
    if (pos < BCAP) packed[b2 * BCAP + pos] = (s4.z << 8) | (t4.z & 255);
    r = atomicAdd(&lhist[b3], 1);
    pos = gbase[b3] + r;
    if (pos < BCAP) packed[b3 * BCAP + pos] = (s4.w << 8) | (t4.w & 255);
  }
}

// ---------------- pass 2: per-bucket LDS counting sort -> CSR + deg + dinv ----------------
__global__ __launch_bounds__(256) void k_build(
    const int* __restrict__ cursor, const int* __restrict__ packed,
    int* __restrict__ adj, int* __restrict__ degarr,
    int* __restrict__ rowptr, float* __restrict__ dinv) {
  __shared__ int ncnt[256];
  __shared__ int noff[256];
  __shared__ int nrank[256];
  __shared__ int ws[4];
  int b = blockIdx.x;
  int tid = threadIdx.x;
  int cntb = cursor[b * CPAD];
  if (cntb > BCAP) cntb = BCAP;
  ncnt[tid] = 0;
  nrank[tid] = 0;
  __syncthreads();
  const int* pk = packed + b * BCAP;
  for (int i = tid; i < cntb; i += 256) atomicAdd(&ncnt[pk[i] & 255], 1);
  __syncthreads();
  {
    int lane = tid & 63, wid = tid >> 6;
    int v = ncnt[tid];
    int x = v;
#pragma unroll
    for (int off = 1; off < 64; off <<= 1) {
      int y = __shfl_up(x, off);
      if (lane >= off) x += y;
    }
    if (lane == 63) ws[wid] = x;
    __syncthreads();
    if (tid == 0) {
      int t0 = ws[0], t1 = ws[1], t2 = ws[2];
      ws[3] = t0 + t1 + t2; ws[2] = t0 + t1; ws[1] = t0; ws[0] = 0;
    }
    __syncthreads();
    noff[tid] = ws[wid] + x - v;
  }
  __syncthreads();
  int n = (b << 8) + tid;
  if (n < N_NODES) {
    int d = ncnt[tid];
    degarr[n] = d;
    rowptr[n] = b * BCAP + noff[tid];
    dinv[n] = rsqrtf(1.0f + (float)d);  // +1 self-loop
  }
  __syncthreads();
  for (int i = tid; i < cntb; i += 256) {
    int e = pk[i];
    int low = e & 255;
    int r = atomicAdd(&nrank[low], 1);
    adj[b * BCAP + noff[low] + r] = e >> 8;
  }
}

// ---------------- MFMA GEMM: g[n][f] = fp16(dinv[n]*(A@W)[n][f]) ----------------
// 256 thr = 4 waves -> 64 rows x 96 cols tile; wave w: rows 16w..16w+15, 6 col-frags.
template<int K, bool A_HALF>
__global__ __launch_bounds__(256) void k_gemm_mfma(
    const void* __restrict__ Av, const float* __restrict__ W,
    const float* __restrict__ dinv, __half* __restrict__ g) {
  constexpr int BM = 64;
  constexpr int LDA = 40;                  // f16 units; 80B pitch (16B-aligned)
  __shared__ _Float16 As[BM][LDA];         // 64 x 32 A-tile
  __shared__ _Float16 Wt[HID][LDA];        // transposed W-tile: [col][k]
  int tid = threadIdx.x;
  int wave = tid >> 6;
  int lane = tid & 63;
  int nbase = blockIdx.x * BM;
  f32x4 acc[6] = {};

  for (int k0 = 0; k0 < K; k0 += 32) {
    {
      int row = tid >> 2;
      int c8 = (tid & 3) * 8;
      int n = nbase + row;
      if (A_HALF) {
        const __half* A = (const __half*)Av;
        uint4 v = make_uint4(0u, 0u, 0u, 0u);
        if (n < N_NODES) v = *reinterpret_cast<const uint4*>(A + (size_t)n * K + k0 + c8);
        *reinterpret_cast<uint4*>(&As[row][c8]) = v;
      } else {
        const float* A = (const float*)Av;
        float4 a0 = make_float4(0.f, 0.f, 0.f, 0.f), a1 = a0;
        if (n < N_NODES) {
          a0 = *reinterpret_cast<const float4*>(A + (size_t)n * K + k0 + c8);
          a1 = *reinterpret_cast<const float4*>(A + (size_t)n * K + k0 + c8 + 4);
        }
        f16x8 hv;
        hv[0] = (_Float16)a0.x; hv[1] = (_Float16)a0.y;
        hv[2] = (_Float16)a0.z; hv[3] = (_Float16)a0.w;
        hv[4] = (_Float16)a1.x; hv[5] = (_Float16)a1.y;
        hv[6] = (_Float16)a1.z; hv[7] = (_Float16)a1.w;
        *reinterpret_cast<f16x8*>(&As[row][c8]) = hv;
      }
    }
#pragma unroll
    for (int i = 0; i < 12; i++) {
      int idx = tid + i * 256;
      int col = idx % HID;
      int k = idx / HID;
      Wt[col][k] = (_Float16)W[(size_t)(k0 + k) * HID + col];
    }
    __syncthreads();
    {
      f16x8 a = *reinterpret_cast<const f16x8*>(&As[wave * 16 + (lane & 15)][(lane >> 4) * 8]);
#pragma unroll
      for (int cb = 0; cb < 6; cb++) {
        f16x8 b = *reinterpret_cast<const f16x8*>(&Wt[cb * 16 + (lane & 15)][(lane >> 4) * 8]);
        acc[cb] = __builtin_amdgcn_mfma_f32_16x16x32_f16(a, b, acc[cb], 0, 0, 0);
      }
    }
    __syncthreads();
  }

#pragma unroll
  for (int r = 0; r < 4; r++) {
    int row = wave * 16 + (lane >> 4) * 4 + r;
    int n = nbase + row;
    if (n < N_NODES) {
      float d = dinv[n];
      __half* gp = g + (size_t)n * HID + (lane & 15);
#pragma unroll
      for (int cb = 0; cb < 6; cb++)
        gp[cb * 16] = __float2half(acc[cb][r] * d);
    }
  }
}

// ---------------- fused aggregate (+ fused classifier when FINAL, via DYNAMIC LDS) ----------------
// R9/R13 form: one dword per lane covers a 192B fp16 row (48 active lanes); one vmem
// request per edge; plain loads; 16/8/4/1 exact-trip unroll; all __shfl unconditional.
// FINAL=1 (launched with 8916B dynamic LDS): stage Wl/bl in LDS, park h row in LDS,
// lanes 0-20 compute out[n][c]. FINAL=0 launched with 0 dynamic LDS -> codegen
// identical to the clean R15 kernel (static __shared__ would be allocated even when
// unused -- that was R16's regression).
template<int FINAL>
__global__ __launch_bounds__(128) void k_aggregate(
    const __half* __restrict__ g, const int* __restrict__ degarr,
    const int* __restrict__ rowptr, const int* __restrict__ adj,
    const float* __restrict__ dinv, const float* __restrict__ b,
    __half* __restrict__ hout, const float* __restrict__ Wl,
    const float* __restrict__ bl, float* __restrict__ out) {
  extern __shared__ float smem[];
  float* wl   = smem;                    // HID*NCLS
  float* bs   = smem + HID * NCLS;       // NCLS
  float* hbuf = smem + HID * NCLS + NCLS;  // 2*HID

  int tid = threadIdx.x;
  if (FINAL) {
    for (int i = tid; i < HID * NCLS; i += 128) wl[i] = Wl[i];
    if (tid < NCLS) bs[tid] = bl[tid];
    __syncthreads();
  }

  int w = tid >> 6;
  int n = blockIdx.x * 2 + w;
  if (!FINAL && n >= N_NODES) return;    // never fires for FINAL (N even)
  int lane = tid & 63;
  bool act = lane < 48;                  // 48 lanes x 4B = 192B row
  int deg = degarr[n];
  const int* al = adj + rowptr[n];
  int myidx = (lane < deg) ? al[lane] : 0;  // coalesced adjacency row load

  const char* gb = (const char*)g;
  int loff = lane * 4;
  float sx, sy;
  {
    unsigned v = act ? *(const unsigned*)(gb + (size_t)n * 192 + loff) : 0u;
    float2 t = __half22float2(*(const __half2*)&v);
    sx = t.x; sy = t.y;
  }

  int dd = deg > 64 ? 64 : deg;
  int j = 0;
  for (; j + 16 <= dd; j += 16) {
    unsigned v[16];
#pragma unroll
    for (int u = 0; u < 16; u++) {
      int idx = __shfl(myidx, j + u);
      v[u] = act ? *(const unsigned*)(gb + (size_t)idx * 192 + loff) : 0u;
    }
#pragma unroll
    for (int u = 0; u < 16; u++) {
      float2 t = __half22float2(*(const __half2*)&v[u]);
      sx += t.x; sy += t.y;
    }
  }
  if (j + 8 <= dd) {
    unsigned v[8];
#pragma unroll
    for (int u = 0; u < 8; u++) {
      int idx = __shfl(myidx, j + u);
      v[u] = act ? *(const unsigned*)(gb + (size_t)idx * 192 + loff) : 0u;
    }
#pragma unroll
    for (int u = 0; u < 8; u++) {
      float2 t = __half22float2(*(const __half2*)&v[u]);
      sx += t.x; sy += t.y;
    }
    j += 8;
  }
  if (j + 4 <= dd) {
    unsigned v[4];
#pragma unroll
    for (int u = 0; u < 4; u++) {
      int idx = __shfl(myidx, j + u);
      v[u] = act ? *(const unsigned*)(gb + (size_t)idx * 192 + loff) : 0u;
    }
#pragma unroll
    for (int u = 0; u < 4; u++) {
      float2 t = __half22float2(*(const __half2*)&v[u]);
      sx += t.x; sy += t.y;
    }
    j += 4;
  }
  for (; j < dd; j++) {
    int idx = __shfl(myidx, j);
    unsigned v = act ? *(const unsigned*)(gb + (size_t)idx * 192 + loff) : 0u;
    float2 t = __half22float2(*(const __half2*)&v);
    sx += t.x; sy += t.y;
  }
  for (; j < deg; j++) {  // deg > 64: essentially impossible, but correct
    int idx = al[j];
    unsigned v = act ? *(const unsigned*)(gb + (size_t)idx * 192 + loff) : 0u;
    float2 t = __half22float2(*(const __half2*)&v);
    sx += t.x; sy += t.y;
  }

  if (act) {
    float d = dinv[n];
    float2 bb = *reinterpret_cast<const float2*>(b + 2 * lane);
    float v0 = d * sx + bb.x;
    float v1 = d * sy + bb.y;
    v0 = v0 > 0.f ? v0 : 0.01f * v0;
    v1 = v1 > 0.f ? v1 : 0.01f * v1;
    if (FINAL) {
      hbuf[w * HID + 2 * lane] = v0;
      hbuf[w * HID + 2 * lane + 1] = v1;
    } else {
      *reinterpret_cast<__half2*>(hout + (size_t)n * HID + 2 * lane) =
          __floats2half2_rn(v0, v1);
    }
  }

  if (FINAL) {
    __syncthreads();   // all 128 threads reach here (no early return in FINAL)
    if (lane < NCLS) {
      float ssum = bs[lane];
#pragma unroll 8
      for (int k = 0; k < HID; k++) ssum += hbuf[w * HID + k] * wl[k * NCLS + lane];
      out[(size_t)n * NCLS + lane] = ssum;
    }
  }
}

extern "C" void kernel_launch(void* const* d_in, const int* in_sizes, int n_in,
                              void* d_out, int out_size, void* d_ws, size_t ws_size,
                              hipStream_t stream) {
  const float* x  = (const float*)d_in[0];
  const int* ei   = (const int*)d_in[1];
  const int* src  = ei;             // edge_index[0]
  const int* tgt  = ei + N_EDGES;   // edge_index[1]
  const float* W1 = (const float*)d_in[2];
  const float* b1 = (const float*)d_in[3];
  const float* W2 = (const float*)d_in[4];
  const float* b2 = (const float*)d_in[5];
  const float* W3 = (const float*)d_in[6];
  const float* b3 = (const float*)d_in[7];
  const float* Wl = (const float*)d_in[8];
  const float* bl = (const float*)d_in[9];
  float* out = (float*)d_out;

  // workspace layout
  float*  dinv   = (float*)d_ws;                            // N
  __half* bufG   = (__half*)(dinv + N_NODES);               // N*96 fp16 (gather payload)
  __half* bufH   = bufG + (size_t)N_NODES * HID;            // N*96 fp16 (h)
  int*    degarr = (int*)(bufH + (size_t)N_NODES * HID);    // N
  int*    rowptr = degarr + N_NODES;                        // N
  int*    cursor = rowptr + N_NODES;                        // NBUCK*CPAD
  int*    packed = cursor + NBUCK * CPAD;                   // NBUCK*BCAP
  int*    adj    = packed + NBUCK * BCAP;                   // NBUCK*BCAP

  // ---- CSR build via 2-level counting sort ----
  k_zero_int<<<(NBUCK * CPAD + 255) / 256, 256, 0, stream>>>(cursor, NBUCK * CPAD);
  k_bin<<<(N_EDGES + 4095) / 4096, 1024, 0, stream>>>(src, tgt, cursor, packed);
  k_build<<<NBUCK, 256, 0, stream>>>(cursor, packed, adj, degarr, rowptr, dinv);

  const int ggrid = (N_NODES + 63) / 64;
  const int agrid = (N_NODES + 1) / 2;
  const size_t final_lds = (size_t)(HID * NCLS + NCLS + 2 * HID) * sizeof(float);

  // ---- layer 1 ----
  k_gemm_mfma<IN_F, false><<<ggrid, 256, 0, stream>>>(x, W1, dinv, bufG);
  k_aggregate<0><<<agrid, 128, 0, stream>>>(bufG, degarr, rowptr, adj, dinv, b1,
                                            bufH, nullptr, nullptr, nullptr);
  // ---- layer 2 ----
  k_gemm_mfma<HID, true><<<ggrid, 256, 0, stream>>>(bufH, W2, dinv, bufG);
  k_aggregate<0><<<agrid, 128, 0, stream>>>(bufG, degarr, rowptr, adj, dinv, b2,
                                            bufH, nullptr, nullptr, nullptr);
  // ---- layer 3 (classifier fused, dynamic LDS only on this dispatch) ----
  k_gemm_mfma<HID, true><<<ggrid, 256, 0, stream>>>(bufH, W3, dinv, bufG);
  k_aggregate<1><<<agrid, 128, final_lds, stream>>>(bufG, degarr, rowptr, adj, dinv, b3,
                                                    nullptr, Wl, bl, out);
}

// Round 19
// 167.137 us; speedup vs baseline: 1.1275x; 1.1275x over previous
//
#include <hip/hip_runtime.h>
#include <hip/hip_fp16.h>

#define N_NODES 50000
#define N_EDGES 800000
#define IN_F 128
#define HID 96
#define NCLS 21
#define NBUCK 196        // coarse bucket = tgt>>8  (49999>>8 = 195)
#define BCAP  4608       // per-bucket capacity: mean 4082, +8 sigma
#define CPAD  16         // cursor stride in ints -> one 64B line per counter

typedef _Float16 hvec2 __attribute__((ext_vector_type(2)));
typedef _Float16 f16x8 __attribute__((ext_vector_type(8)));
typedef float f32x4 __attribute__((ext_vector_type(4)));

__device__ __forceinline__ float fdot2f(__half2 a, __half2 b, float c) {
#if __has_builtin(__builtin_amdgcn_fdot2)
  union { __half2 h; hvec2 v; } ua, ub;
  ua.h = a; ub.h = b;
  return __builtin_amdgcn_fdot2(ua.v, ub.v, c, false);
#else
  float2 fa = __half22float2(a), fb = __half22float2(b);
  return c + fa.x * fb.x + fa.y * fb.y;
#endif
}

// ---------------- zero ----------------
__global__ void k_zero_int(int* __restrict__ p, int n) {
  int i = blockIdx.x * blockDim.x + threadIdx.x;
  if (i < n) p[i] = 0;
}

// ---------------- pass 1: bin edges by tgt>>8 ----------------
__global__ __launch_bounds__(1024) void k_bin(
    const int* __restrict__ src, const int* __restrict__ tgt,
    int* __restrict__ cursor, int* __restrict__ packed) {
  __shared__ int lhist[NBUCK];
  __shared__ int gbase[NBUCK];
  int tid = threadIdx.x;
  if (tid < NBUCK) lhist[tid] = 0;
  __syncthreads();
  int me = blockIdx.x * 4096 + tid * 4;
  int4 t4, s4;
  int b0 = 0, b1 = 0, b2 = 0, b3 = 0;
  bool valid = me < N_EDGES;
  if (valid) {
    t4 = *reinterpret_cast<const int4*>(tgt + me);
    s4 = *reinterpret_cast<const int4*>(src + me);
    b0 = t4.x >> 8; b1 = t4.y >> 8; b2 = t4.z >> 8; b3 = t4.w >> 8;
    atomicAdd(&lhist[b0], 1); atomicAdd(&lhist[b1], 1);
    atomicAdd(&lhist[b2], 1); atomicAdd(&lhist[b3], 1);
  }
  __syncthreads();
  if (tid < NBUCK) {
    int c = lhist[tid];
    gbase[tid] = c ? atomicAdd(&cursor[tid * CPAD], c) : 0;
    lhist[tid] = 0;
  }
  __syncthreads();
  if (valid) {
    int r, pos;
    r = atomicAdd(&lhist[b0], 1);
    pos = gbase[b0] + r;
    if (pos < BCAP) packed[b0 * BCAP + pos] = (s4.x << 8) | (t4.x & 255);
    r = atomicAdd(&lhist[b1], 1);
    pos = gbase[b1] + r;
    if (pos < BCAP) packed[b1 * BCAP + pos] = (s4.y << 8) | (t4.y & 255);
    r = atomicAdd(&lhist[b2], 1);
    pos = gbase[b2] + r;
    if (pos < BCAP) packed[b2 * BCAP + pos] = (s4.z << 8) | (t4.z & 255);
    r = atomicAdd(&lhist[b3], 1);
    pos = gbase[b3] + r;
    if (pos < BCAP) packed[b3 * BCAP + pos] = (s4.w << 8) | (t4.w & 255);
  }
}

// ---------------- pass 2: per-bucket LDS counting sort -> CSR + deg + dinv ----------------
__global__ __launch_bounds__(256) void k_build(
    const int* __restrict__ cursor, const int* __restrict__ packed,
    int* __restrict__ adj, int* __restrict__ degarr,
    int* __restrict__ rowptr, float* __restrict__ dinv) {
  __shared__ int ncnt[256];
  __shared__ int noff[256];
  __shared__ int nrank[256];
  __shared__ int ws[4];
  int b = blockIdx.x;
  int tid = threadIdx.x;
  int cntb = cursor[b * CPAD];
  if (cntb > BCAP) cntb = BCAP;
  ncnt[tid] = 0;
  nrank[tid] = 0;
  __syncthreads();
  const int* pk = packed + b * BCAP;
  for (int i = tid; i < cntb; i += 256) atomicAdd(&ncnt[pk[i] & 255], 1);
  __syncthreads();
  {
    int lane = tid & 63, wid = tid >> 6;
    int v = ncnt[tid];
    int x = v;
#pragma unroll
    for (int off = 1; off < 64; off <<= 1) {
      int y = __shfl_up(x, off);
      if (lane >= off) x += y;
    }
    if (lane == 63) ws[wid] = x;
    __syncthreads();
    if (tid == 0) {
      int t0 = ws[0], t1 = ws[1], t2 = ws[2];
      ws[3] = t0 + t1 + t2; ws[2] = t0 + t1; ws[1] = t0; ws[0] = 0;
    }
    __syncthreads();
    noff[tid] = ws[wid] + x - v;
  }
  __syncthreads();
  int n = (b << 8) + tid;
  if (n < N_NODES) {
    int d = ncnt[tid];
    degarr[n] = d;
    rowptr[n] = b * BCAP + noff[tid];
    dinv[n] = rsqrtf(1.0f + (float)d);  // +1 self-loop
  }
  __syncthreads();
  for (int i = tid; i < cntb; i += 256) {
    int e = pk[i];
    int low = e & 255;
    int r = atomicAdd(&nrank[low], 1);
    adj[b * BCAP + noff[low] + r] = e >> 8;
  }
}

// ---------------- MFMA GEMM: g[n][f] = fp16(dinv[n]*(A@W)[n][f]) ----------------
// 256 thr = 4 waves -> 64 rows x 96 cols tile; wave w: rows 16w..16w+15, 6 col-frags.
// v_mfma_f32_16x16x32_f16: A lane=(row=l&15, k=(l>>4)*8+i); B lane=(col=l&15, k=(l>>4)*8+i);
// D lane=(col=l&15, row=(l>>4)*4+reg) [verified m89 mapping].
template<int K, bool A_HALF>
__global__ __launch_bounds__(256) void k_gemm_mfma(
    const void* __restrict__ Av, const float* __restrict__ W,
    const float* __restrict__ dinv, __half* __restrict__ g) {
  constexpr int BM = 64;
  constexpr int LDA = 40;                  // f16 units; 80B pitch (16B-aligned)
  __shared__ _Float16 As[BM][LDA];         // 64 x 32 A-tile
  __shared__ _Float16 Wt[HID][LDA];        // transposed W-tile: [col][k]
  int tid = threadIdx.x;
  int wave = tid >> 6;
  int lane = tid & 63;
  int nbase = blockIdx.x * BM;
  f32x4 acc[6] = {};

  for (int k0 = 0; k0 < K; k0 += 32) {
    // ---- stage A (64x32 -> f16) : one 16B chunk per thread ----
    {
      int row = tid >> 2;
      int c8 = (tid & 3) * 8;
      int n = nbase + row;
      if (A_HALF) {
        const __half* A = (const __half*)Av;
        uint4 v = make_uint4(0u, 0u, 0u, 0u);
        if (n < N_NODES) v = *reinterpret_cast<const uint4*>(A + (size_t)n * K + k0 + c8);
        *reinterpret_cast<uint4*>(&As[row][c8]) = v;
      } else {
        const float* A = (const float*)Av;
        float4 a0 = make_float4(0.f, 0.f, 0.f, 0.f), a1 = a0;
        if (n < N_NODES) {
          a0 = *reinterpret_cast<const float4*>(A + (size_t)n * K + k0 + c8);
          a1 = *reinterpret_cast<const float4*>(A + (size_t)n * K + k0 + c8 + 4);
        }
        f16x8 hv;
        hv[0] = (_Float16)a0.x; hv[1] = (_Float16)a0.y;
        hv[2] = (_Float16)a0.z; hv[3] = (_Float16)a0.w;
        hv[4] = (_Float16)a1.x; hv[5] = (_Float16)a1.y;
        hv[6] = (_Float16)a1.z; hv[7] = (_Float16)a1.w;
        *reinterpret_cast<f16x8*>(&As[row][c8]) = hv;
      }
    }
    // ---- stage W transposed (32 x 96 -> Wt[col][k] f16): 3072 elems / 256 thr ----
#pragma unroll
    for (int i = 0; i < 12; i++) {
      int idx = tid + i * 256;
      int col = idx % HID;
      int k = idx / HID;
      Wt[col][k] = (_Float16)W[(size_t)(k0 + k) * HID + col];
    }
    __syncthreads();
    // ---- MFMA: 1 A-frag read + 6 B-frag reads + 6 MFMA per wave ----
    {
      f16x8 a = *reinterpret_cast<const f16x8*>(&As[wave * 16 + (lane & 15)][(lane >> 4) * 8]);
#pragma unroll
      for (int cb = 0; cb < 6; cb++) {
        f16x8 b = *reinterpret_cast<const f16x8*>(&Wt[cb * 16 + (lane & 15)][(lane >> 4) * 8]);
        acc[cb] = __builtin_amdgcn_mfma_f32_16x16x32_f16(a, b, acc[cb], 0, 0, 0);
      }
    }
    __syncthreads();
  }

  // ---- epilogue: scale by dinv, fp16 store ----
#pragma unroll
  for (int r = 0; r < 4; r++) {
    int row = wave * 16 + (lane >> 4) * 4 + r;
    int n = nbase + row;
    if (n < N_NODES) {
      float d = dinv[n];
      __half* gp = g + (size_t)n * HID + (lane & 15);
#pragma unroll
      for (int cb = 0; cb < 6; cb++)
        gp[cb * 16] = __float2half(acc[cb][r] * d);
    }
  }
}

// ---------------- fused aggregate: h = fp16(leaky(dinv*(g[n] + sum_in g[src]) + b)) ----------------
// R9/R13 form (best measured): one dword per lane covers a 192B fp16 row (48 active
// lanes); one vmem request per edge; plain loads (nt demoted L2, R14); 16/8/4/1
// exact-trip unroll; all __shfl unconditional (ds_bpermute source-lane rule, R11).
__global__ __launch_bounds__(128) void k_aggregate(
    const __half* __restrict__ g, const int* __restrict__ degarr,
    const int* __restrict__ rowptr, const int* __restrict__ adj,
    const float* __restrict__ dinv, const float* __restrict__ b,
    __half* __restrict__ hout) {
  int n = blockIdx.x * 2 + (threadIdx.x >> 6);
  if (n >= N_NODES) return;
  int lane = threadIdx.x & 63;
  bool act = lane < 48;                    // 48 lanes x 4B = 192B row
  int deg = degarr[n];
  const int* al = adj + rowptr[n];
  int myidx = (lane < deg) ? al[lane] : 0;  // coalesced adjacency row load

  const char* gb = (const char*)g;
  int loff = lane * 4;
  float sx, sy;
  {
    unsigned v = act ? *(const unsigned*)(gb + (size_t)n * 192 + loff) : 0u;
    float2 t = __half22float2(*(const __half2*)&v);
    sx = t.x; sy = t.y;
  }

  int dd = deg > 64 ? 64 : deg;
  int j = 0;
  for (; j + 16 <= dd; j += 16) {
    unsigned v[16];
#pragma unroll
    for (int u = 0; u < 16; u++) {
      int idx = __shfl(myidx, j + u);
      v[u] = act ? *(const unsigned*)(gb + (size_t)idx * 192 + loff) : 0u;
    }
#pragma unroll
    for (int u = 0; u < 16; u++) {
      float2 t = __half22float2(*(const __half2*)&v[u]);
      sx += t.x; sy += t.y;
    }
  }
  if (j + 8 <= dd) {
    unsigned v[8];
#pragma unroll
    for (int u = 0; u < 8; u++) {
      int idx = __shfl(myidx, j + u);
      v[u] = act ? *(const unsigned*)(gb + (size_t)idx * 192 + loff) : 0u;
    }
#pragma unroll
    for (int u = 0; u < 8; u++) {
      float2 t = __half22float2(*(const __half2*)&v[u]);
      sx += t.x; sy += t.y;
    }
    j += 8;
  }
  if (j + 4 <= dd) {
    unsigned v[4];
#pragma unroll
    for (int u = 0; u < 4; u++) {
      int idx = __shfl(myidx, j + u);
      v[u] = act ? *(const unsigned*)(gb + (size_t)idx * 192 + loff) : 0u;
    }
#pragma unroll
    for (int u = 0; u < 4; u++) {
      float2 t = __half22float2(*(const __half2*)&v[u]);
      sx += t.x; sy += t.y;
    }
    j += 4;
  }
  for (; j < dd; j++) {
    int idx = __shfl(myidx, j);
    unsigned v = act ? *(const unsigned*)(gb + (size_t)idx * 192 + loff) : 0u;
    float2 t = __half22float2(*(const __half2*)&v);
    sx += t.x; sy += t.y;
  }
  for (; j < deg; j++) {  // deg > 64: essentially impossible, but correct
    int idx = al[j];
    unsigned v = act ? *(const unsigned*)(gb + (size_t)idx * 192 + loff) : 0u;
    float2 t = __half22float2(*(const __half2*)&v);
    sx += t.x; sy += t.y;
  }

  if (act) {
    float d = dinv[n];
    float2 bb = *reinterpret_cast<const float2*>(b + 2 * lane);
    float v0 = d * sx + bb.x;
    float v1 = d * sy + bb.y;
    v0 = v0 > 0.f ? v0 : 0.01f * v0;
    v1 = v1 > 0.f ? v1 : 0.01f * v1;
    *reinterpret_cast<__half2*>(hout + (size_t)n * HID + 2 * lane) =
        __floats2half2_rn(v0, v1);
  }
}

// ---------------- final linear: out = H @ Wl + bl (fp16 H, dot2) ----------------
__global__ __launch_bounds__(256) void k_final(
    const __half* __restrict__ H, const float* __restrict__ Wl,
    const float* __restrict__ bl, float* __restrict__ out) {
  __shared__ __half2 w2[HID / 2][NCLS];   // k-pairs of Wl
  __shared__ float bs[NCLS];
  int tid = threadIdx.x;
  for (int i = tid; i < (HID / 2) * NCLS; i += 256) {
    int r2 = i / NCLS;
    int c = i - r2 * NCLS;
    w2[r2][c] = __floats2half2_rn(Wl[(size_t)(2 * r2) * NCLS + c],
                                  Wl[(size_t)(2 * r2 + 1) * NCLS + c]);
  }
  if (tid < NCLS) bs[tid] = bl[tid];
  __syncthreads();
  int idx = blockIdx.x * 256 + tid;
  if (idx >= N_NODES * NCLS) return;
  int n = idx / NCLS;
  int c = idx - n * NCLS;
  const __half2* a2 = reinterpret_cast<const __half2*>(H + (size_t)n * HID);
  float s = bs[c];
#pragma unroll
  for (int k2 = 0; k2 < HID / 2; k2++) s = fdot2f(a2[k2], w2[k2][c], s);
  out[idx] = s;
}

extern "C" void kernel_launch(void* const* d_in, const int* in_sizes, int n_in,
                              void* d_out, int out_size, void* d_ws, size_t ws_size,
                              hipStream_t stream) {
  const float* x  = (const float*)d_in[0];
  const int* ei   = (const int*)d_in[1];
  const int* src  = ei;             // edge_index[0]
  const int* tgt  = ei + N_EDGES;   // edge_index[1]
  const float* W1 = (const float*)d_in[2];
  const float* b1 = (const float*)d_in[3];
  const float* W2 = (const float*)d_in[4];
  const float* b2 = (const float*)d_in[5];
  const float* W3 = (const float*)d_in[6];
  const float* b3 = (const float*)d_in[7];
  const float* Wl = (const float*)d_in[8];
  const float* bl = (const float*)d_in[9];
  float* out = (float*)d_out;

  // workspace layout
  float*  dinv   = (float*)d_ws;                            // N
  __half* bufG   = (__half*)(dinv + N_NODES);               // N*96 fp16 (gather payload)
  __half* bufH   = bufG + (size_t)N_NODES * HID;            // N*96 fp16 (h)
  int*    degarr = (int*)(bufH + (size_t)N_NODES * HID);    // N
  int*    rowptr = degarr + N_NODES;                        // N
  int*    cursor = rowptr + N_NODES;                        // NBUCK*CPAD
  int*    packed = cursor + NBUCK * CPAD;                   // NBUCK*BCAP
  int*    adj    = packed + NBUCK * BCAP;                   // NBUCK*BCAP

  // ---- CSR build via 2-level counting sort ----
  k_zero_int<<<(NBUCK * CPAD + 255) / 256, 256, 0, stream>>>(cursor, NBUCK * CPAD);
  k_bin<<<(N_EDGES + 4095) / 4096, 1024, 0, stream>>>(src, tgt, cursor, packed);
  k_build<<<NBUCK, 256, 0, stream>>>(cursor, packed, adj, degarr, rowptr, dinv);

  const int ggrid = (N_NODES + 63) / 64;
  const int agrid = (N_NODES + 1) / 2;

  // ---- layer 1 ----
  k_gemm_mfma<IN_F, false><<<ggrid, 256, 0, stream>>>(x, W1, dinv, bufG);
  k_aggregate<<<agrid, 128, 0, stream>>>(bufG, degarr, rowptr, adj, dinv, b1, bufH);
  // ---- layer 2 ----
  k_gemm_mfma<HID, true><<<ggrid, 256, 0, stream>>>(bufH, W2, dinv, bufG);
  k_aggregate<<<agrid, 128, 0, stream>>>(bufG, degarr, rowptr, adj, dinv, b2, bufH);
  // ---- layer 3 ----
  k_gemm_mfma<HID, true><<<ggrid, 256, 0, stream>>>(bufH, W3, dinv, bufG);
  k_aggregate<<<agrid, 128, 0, stream>>>(bufG, degarr, rowptr, adj, dinv, b3, bufH);

  // ---- classifier ----
  k_final<<<(N_NODES * NCLS + 255) / 256, 256, 0, stream>>>(bufH, Wl, bl, out);
}